// Round 15
// baseline (50630.701 us; speedup 1.0000x reference)
//
#include <hip/hip_runtime.h>
#include <hip/hip_cooperative_groups.h>
#include <hip/hip_bf16.h>
#include <hip/hip_fp16.h>
#include <math.h>

namespace cg = cooperative_groups;

#define CS 96      // source len
#define CT 96      // target len
#define CE 256     // embed
#define CH 512     // hidden
#define CH2 1024
#define CH3 1536
#define CV 32000
#define CXD 1280   // E + 2H

typedef unsigned int u32;
typedef unsigned short u16;
typedef unsigned long long u64;
typedef __attribute__((ext_vector_type(4))) int i32x4;

__device__ __forceinline__ float sigm(float x){ return 1.f/(1.f+expf(-x)); }

__device__ __forceinline__ float dot2f(u32 a, u32 b, float c){
#if __has_builtin(__builtin_amdgcn_fdot2)
  typedef _Float16 hv2 __attribute__((ext_vector_type(2)));
  hv2 x = __builtin_bit_cast(hv2, a), y = __builtin_bit_cast(hv2, b);
  return __builtin_amdgcn_fdot2(x, y, c, false);
#else
  __half2 x = __builtin_bit_cast(__half2, a), y = __builtin_bit_cast(__half2, b);
  return c + __half2float(x.x)*__half2float(y.x) + __half2float(x.y)*__half2float(y.y);
#endif
}

__device__ __forceinline__ u32 packh2(float a, float b){
  return (u32)__half_as_ushort(__float2half(a)) | ((u32)__half_as_ushort(__float2half(b)) << 16);
}

// lgkm-only barrier inside the cov block (drains LDS ops, not global stores)
#define COVBAR() do{ asm volatile("s_waitcnt lgkmcnt(0)" ::: "memory"); \
                     __builtin_amdgcn_sched_barrier(0); \
                     __builtin_amdgcn_s_barrier(); \
                     __builtin_amdgcn_sched_barrier(0); }while(0)

// ================= pre-kernels (both paths) =================
__global__ void k_embed(const int* iseq, const int* oseq, const float* ee, const float* de,
                        float* x_enc, float* x_dec){
  int s = blockIdx.x, d = threadIdx.x;
  x_enc[s*CE+d] = ee[(long)iseq[s]*CE + d];
  x_dec[s*CE+d] = de[(long)oseq[s]*CE + d];
}

__global__ void k_gi(const float* Wf, const float* bf, const float* Wb, const float* bb,
                     const float* x_enc, float* gf, float* gb){
  int idx = blockIdx.x*256 + threadIdx.x;
  int dir = idx / (CS*CH3);
  int rem = idx - dir*(CS*CH3);
  int s = rem / CH3, r = rem - s*CH3;
  const float* W = dir ? Wb : Wf;
  const float* b = dir ? bb : bf;
  const float* x = x_enc + s*CE;
  const float* w = W + (long)r*CE;
  float acc = b[r];
  #pragma unroll 8
  for (int k=0;k<CE;k++) acc += w[k]*x[k];
  (dir ? gb : gf)[s*CH3 + r] = acc;
}

__global__ void k_cvt(const float* w, u16* o, int n){
  int i = blockIdx.x*blockDim.x + threadIdx.x;
  int stride = gridDim.x*blockDim.x;
  for (; i<n; i+=stride){
    union { float f; u32 u; } v; v.f = w[i];
    u32 r = (v.u + 0x7fffu + ((v.u>>16)&1u)) >> 16;
    o[i] = (u16)r;
  }
}

__global__ void k_cvt_cov(const float* Wic, u32* wic16P){
  int i = blockIdx.x*256 + threadIdx.x;     // 256*512 total
  int kp = i >> 9, r = i & 511;
  float a = Wic[(size_t)r*CH3 + CH2 + 2*kp];
  float b = Wic[(size_t)r*CH3 + CH2 + 2*kp + 1];
  wic16P[(size_t)kp*512 + r] = packh2(a, b);
}

__global__ void k_quant(const float* Whc, uint4* w8m, float* rs){
  int r = blockIdx.x;          // 512 blocks x 64 threads
  int l = threadIdx.x;
  const float* wr = Whc + (size_t)r*CH;
  float m = 0.f;
  for (int k=l; k<CH; k+=64) m = fmaxf(m, fabsf(wr[k]));
  for (int d=1; d<64; d<<=1) m = fmaxf(m, __shfl_xor(m,d));
  float sc = (m > 0.f) ? (127.f/m) : 0.f;
  if (l < 32){
    int kb = l>>2, q = l&3;
    u32 wv[4];
    #pragma unroll
    for (int wi=0;wi<4;wi++){
      u32 p = 0;
      #pragma unroll
      for (int j=0;j<4;j++){
        int v = (int)rintf(wr[kb*64 + q*16 + wi*4 + j]*sc);
        v = max(-127, min(127, v));
        p |= (u32)(v & 255) << (8*j);
      }
      wv[wi] = p;
    }
    int tile = (r>>4)*8 + kb;
    int lane = q*16 + (r&15);
    w8m[(size_t)tile*64 + lane] = make_uint4(wv[0],wv[1],wv[2],wv[3]);
  }
  if (l==0) rs[r] = m/(127.f*127.f);
}

// ================= fallback-path kernels (r14, proven) =================
__global__ void k_init(float* cov_last){
  int i = threadIdx.x;
  for (int j = i; j < CH; j += 256) cov_last[j] = 0.f;
}

__global__ void k_enc_step(int s, const float* Whf, const float* bhf, const float* Whb, const float* bhb,
                           const float* gf, const float* gb, float* outf, float* outb){
  int wg = blockIdx.x;
  int dir = wg >> 3;
  int jb = (wg & 7)*64;
  int t = threadIdx.x;
  int j = jb + (t>>2);
  int c0 = (t&3)*128;
  const float* Whh = dir ? Whb : Whf;
  const float* bhh = dir ? bhb : bhf;
  const float* gi  = dir ? gb : gf;
  float* o = dir ? outb : outf;
  int pos = dir ? (CS-1-s) : s;
  const float* hp = (s>0) ? (o + (dir ? (pos+1)*CH : (s-1)*CH)) : nullptr;
  float ar=0.f, az=0.f, an=0.f;
  if (s > 0){
    const float* wr = Whh + (long)j*CH;
    const float* wz = Whh + (long)(j+CH)*CH;
    const float* wn = Whh + (long)(j+2*CH)*CH;
    #pragma unroll 4
    for (int k=c0;k<c0+128;k++){
      float h = hp[k];
      ar += wr[k]*h; az += wz[k]*h; an += wn[k]*h;
    }
  }
  ar += __shfl_xor(ar,1); ar += __shfl_xor(ar,2);
  az += __shfl_xor(az,1); az += __shfl_xor(az,2);
  an += __shfl_xor(an,1); an += __shfl_xor(an,2);
  if ((t&3)==0){
    const float* g = gi + pos*CH3;
    float hpj = (s>0) ? hp[j] : 0.f;
    float r = sigm(g[j]       + ar + bhh[j]);
    float z = sigm(g[j+CH]    + az + bhh[j+CH]);
    float n = tanhf(g[j+2*CH] + r*(an + bhh[j+2*CH]));
    o[pos*CH + j] = (1.f-z)*n + z*hpj;
  }
}

__global__ void k_prep2(const float* ua, const float* Wic, const float* outf, const float* outb,
                        float* ua_enc, float* Aenc, float* h_carry){
  int idx = blockIdx.x*256 + threadIdx.x;
  if (idx < 2*CS*CH){
    int which = idx / (CS*CH);
    int rem = idx - which*(CS*CH);
    int s = rem / CH, r = rem - s*CH;
    const float* of = outf + s*CH;
    const float* ob = outb + s*CH;
    const float* w = which ? (Wic + (long)r*CH3) : (ua + (long)r*CH2);
    float acc = 0.f;
    #pragma unroll 4
    for (int k=0;k<CH;k++) acc += w[k]*of[k];
    #pragma unroll 4
    for (int k=0;k<CH;k++) acc += w[CH+k]*ob[k];
    (which ? Aenc : ua_enc)[s*CH + r] = acc;
  } else if (idx < 2*CS*CH + CH){
    int j = idx - 2*CS*CH;
    h_carry[j] = outf[(CS-1)*CH + j];
  }
}

__global__ void k_wah(const float* wa, const float* h, float* wah){
  int j = blockIdx.x*64 + (threadIdx.x>>2);
  int c0 = (threadIdx.x&3)*128;
  const float* w = wa + (long)j*CH;
  float acc = 0.f;
  #pragma unroll 4
  for (int k=c0;k<c0+128;k++) acc += w[k]*h[k];
  acc += __shfl_xor(acc,1); acc += __shfl_xor(acc,2);
  if ((threadIdx.x&3)==0) wah[j] = acc;
}

__global__ void k_attn(int t, const float* vc, const float* va,
                       const float* ua_enc, const float* cov_vec, const float* wah, float* e){
  int s = blockIdx.x, tid = threadIdx.x;
  __shared__ float red[4];
  float sum = 0.f;
  #pragma unroll
  for (int jj=0;jj<2;jj++){
    int j = tid + jj*256;
    float acc = ua_enc[s*CH + j] + wah[j];
    if (t > 0){
      const float* v = vc + (long)j*CH;
      const float* cvs = cov_vec + s*CH;
      #pragma unroll 4
      for (int k=0;k<CH;k++) acc += v[k]*cvs[k];
    }
    sum += va[j]*tanhf(acc);
  }
  for (int m=1;m<64;m<<=1) sum += __shfl_xor(sum,m);
  if ((tid&63)==0) red[tid>>6] = sum;
  __syncthreads();
  if (tid==0) e[s] = red[0]+red[1]+red[2]+red[3];
}

__global__ void k_soft(const float* e, const float* outf, const float* outb, float* alpha, float* ctx){
  int tid = threadIdx.x; // 128
  __shared__ float al[CS];
  __shared__ float rmax[2], rsum[2];
  float v = (tid<CS) ? e[tid] : -1e30f;
  float m = v;
  for (int k=1;k<64;k<<=1) m = fmaxf(m, __shfl_xor(m,k));
  if ((tid&63)==0) rmax[tid>>6] = m;
  __syncthreads();
  float gm = fmaxf(rmax[0], rmax[1]);
  float ex = (tid<CS) ? expf(v-gm) : 0.f;
  float sm2 = ex;
  for (int k=1;k<64;k<<=1) sm2 += __shfl_xor(sm2,k);
  if ((tid&63)==0) rsum[tid>>6] = sm2;
  __syncthreads();
  float inv = 1.f/(rsum[0]+rsum[1]);
  if (tid<CS){ float a = ex*inv; al[tid] = a; alpha[tid] = a; }
  __syncthreads();
  #pragma unroll
  for (int k=0;k<8;k++){
    int d = k*128 + tid;
    const float* src = (d<CH) ? outf : outb;
    int dd = (d<CH) ? d : d-CH;
    float acc = 0.f;
    for (int s2=0;s2<CS;s2++) acc += al[s2]*src[s2*CH+dd];
    ctx[d] = acc;
  }
}

__global__ void k_gru(int t, const float* Wi, const float* bi, const float* Wh, const float* bh,
                      const float* ctx, const float* x_dec, const float* h_carry, float* h_cur){
  int wg = blockIdx.x, tid = threadIdx.x;
  int j = wg*8 + (tid>>5);
  int ln = tid&31;
  const float* xd = x_dec + t*CE;
  float ar=0.f, az=0.f, an=0.f;
  {
    int c0 = ln*40;
    const float* wr = Wi + (long)j*CXD;
    const float* wz = Wi + (long)(j+CH)*CXD;
    const float* wn = Wi + (long)(j+2*CH)*CXD;
    for (int k=c0;k<c0+40;k++){
      float x = (k<CH2) ? ctx[k] : xd[k-CH2];
      ar += wr[k]*x; az += wz[k]*x; an += wn[k]*x;
    }
  }
  float hr=0.f, hz=0.f, hn2=0.f;
  {
    int c0 = ln*16;
    const float* wr = Wh + (long)j*CH;
    const float* wz = Wh + (long)(j+CH)*CH;
    const float* wn = Wh + (long)(j+2*CH)*CH;
    for (int k=c0;k<c0+16;k++){
      float hv = h_carry[k];
      hr += wr[k]*hv; hz += wz[k]*hv; hn2 += wn[k]*hv;
    }
  }
  for (int m=1;m<32;m<<=1){
    ar+=__shfl_xor(ar,m); az+=__shfl_xor(az,m); an+=__shfl_xor(an,m);
    hr+=__shfl_xor(hr,m); hz+=__shfl_xor(hz,m); hn2+=__shfl_xor(hn2,m);
  }
  if (ln==0){
    float hprev = h_carry[j];
    float r = sigm(ar + bi[j]       + hr + bh[j]);
    float z = sigm(az + bi[j+CH]    + hz + bh[j+CH]);
    float n = tanhf(an + bi[j+2*CH] + r*(hn2 + bh[j+2*CH]));
    h_cur[j] = (1.f-z)*n + z*hprev;
  }
}

template<int BF16>
__launch_bounds__(512, 2)
__global__ void k_tail(int t, const void* Wv, const float* lb, const float* h_cur, const float* ctx,
                       float* out, const float* wa, float* wah,
                       const uint4* w8m, const float* rs, const u32* wic16P,
                       const float* bic, const float* bhc,
                       const float* Aenc, const float* alpha,
                       float* cov_vec, float* cov_last, float* h_carry){
  int b = blockIdx.x, tid = threadIdx.x;

  if (b >= 3){
    int ln = tid&63;
    int gw = (b-3)*8 + (tid>>6);
    float x[24];
    #pragma unroll
    for (int k=0;k<24;k++){
      int c = k*64 + ln;
      x[k] = (c<CH) ? h_cur[c] : ctx[c-CH];
    }
    for (int r=gw; r<CV; r+=800){
      float acc = 0.f;
      if (BF16){
        const u16* w = (const u16*)Wv + (long)r*CH3;
        #pragma unroll
        for (int k=0;k<24;k++){
          u32 u = (u32)w[k*64+ln] << 16;
          acc += __uint_as_float(u)*x[k];
        }
      } else {
        const float* w = (const float*)Wv + (long)r*CH3;
        #pragma unroll
        for (int k=0;k<24;k++) acc += w[k*64+ln]*x[k];
      }
      for (int m=1;m<64;m<<=1) acc += __shfl_xor(acc,m);
      if (ln==0) out[(long)t*CV + r] = acc + lb[r];
    }
    return;
  }

  if (b >= 1){
    if (t > 0){
      int j = (b-1)*256 + (tid>>1);
      int cq = (tid&1)*256;
      const float* w = wa + (long)j*CH;
      float acc = 0.f;
      #pragma unroll 4
      for (int k=cq;k<cq+256;k++) acc += w[k]*h_cur[k];
      acc += __shfl_xor(acc,1);
      if ((tid&1)==0) wah[j] = acc;
    }
    return;
  }

  const float* h_dec = (t==0) ? h_carry : h_cur;
  int w = tid >> 6;
  int l = tid & 63;

  __shared__ u32 part_l[512];
  __shared__ __align__(16) u32 h8w[128];
  __shared__ u32 hd16[256];
  __shared__ float al_l[CS];

  if (tid < CS) al_l[tid] = alpha[tid];
  if (tid < 256) hd16[tid] = packh2(h_dec[2*tid], h_dec[2*tid+1]);
  __syncthreads();

  float bacc_r = 0.f;
  {
    const u32* bw = wic16P + tid;
    #pragma unroll 8
    for (int kp=0;kp<256;kp++)
      bacc_r = dot2f(bw[(size_t)kp*512], hd16[kp], bacc_r);
  }

  i32x4 af[4][8];
  {
    const i32x4* wp = (const i32x4*)w8m;
    #pragma unroll
    for (int j=0;j<4;j++){
      #pragma unroll
      for (int kb=0;kb<8;kb++)
        af[j][kb] = wp[((size_t)((4*w+j)*8+kb))*64 + l];
      asm volatile("" ::: "memory");
    }
  }

  float bsum_r = bic[tid] + bhc[tid];
  float rs_r = rs[tid];
  float a_next = Aenc[tid];
  cov_vec[tid] = tanhf(cov_last[tid]);
  if (t > 0) h_carry[tid] = h_dec[tid];
  __syncthreads();

  for (int s=0;s<CS;s++){
    if (s > 0){
      i32x4 acc0={0,0,0,0}, acc1={0,0,0,0}, acc2={0,0,0,0}, acc3={0,0,0,0};
      #pragma unroll
      for (int kb=0;kb<8;kb++){
        i32x4 bfr = *(const i32x4*)&h8w[kb*16 + (l>>4)*4];
        acc0 = __builtin_amdgcn_mfma_i32_16x16x64_i8(af[0][kb], bfr, acc0, 0,0,0);
        acc1 = __builtin_amdgcn_mfma_i32_16x16x64_i8(af[1][kb], bfr, acc1, 0,0,0);
        acc2 = __builtin_amdgcn_mfma_i32_16x16x64_i8(af[2][kb], bfr, acc2, 0,0,0);
        acc3 = __builtin_amdgcn_mfma_i32_16x16x64_i8(af[3][kb], bfr, acc3, 0,0,0);
      }
      if ((l & 15) == 0){
        int rq = l >> 4;
        *(i32x4*)&part_l[(4*w+0)*16 + rq*4] = acc0;
        *(i32x4*)&part_l[(4*w+1)*16 + rq*4] = acc1;
        *(i32x4*)&part_l[(4*w+2)*16 + rq*4] = acc2;
        *(i32x4*)&part_l[(4*w+3)*16 + rq*4] = acc3;
      }
    }
    COVBAR();
    {
      float T = (s > 0) ? (float)(int)part_l[tid] * rs_r : 0.f;
      float a_cur = a_next;
      if (s < CS-1) a_next = Aenc[(s+1)*CH + tid];
      float h = tanhf(T + al_l[s]*(a_cur + bacc_r) + bsum_r);
      if (s < CS-1){
        int q = (int)rintf(h * 127.f);
        u32 bq = (u32)(q & 255);
        u32 p01 = bq | (__shfl_xor(bq,1) << 8);
        u32 p = p01 | (__shfl_xor(p01,2) << 16);
        if ((tid & 3) == 0) h8w[tid >> 2] = p;
        cov_vec[(s+1)*CH + tid] = tanhf(h);
      } else {
        cov_last[tid] = h;
      }
    }
    COVBAR();
  }
}

// ================= the cooperative mega kernel =================
struct MP {
  const float *Whf,*bhf,*Whb,*bhb,*gf,*gb;
  float *outf,*outb;
  const float *ua,*Wic;
  float *ua_enc,*Aenc,*h_carry;
  const float *wa;
  float *wah;
  const float *vc,*va;
  float *e,*alpha,*ctx;
  const float *Wid,*bid2,*Whd,*bhd2,*x_dec;
  float *h_cur;
  const void *Wv; const float *lb;
  float *outp,*lpart;
  const uint4 *w8m; const float *rs; const u32 *wic16P;
  const float *bic,*bhc;
  float *cov_vec,*cov_last;
};

template<int BF16>
__launch_bounds__(512, 2)
__global__ void k_mega(MP p){
  cg::grid_group gg = cg::this_grid();
  int b = blockIdx.x, tid = threadIdx.x;
  int NB = gridDim.x;

  __shared__ float srd[8];
  __shared__ float al96[CS];
  __shared__ u32 part_l[512];
  __shared__ __align__(16) u32 h8w[128];
  __shared__ u32 hd16[256];
  __shared__ float ldc[CH2];
  __shared__ float ldh[CH];

  // ---------- encoder: 96 steps ----------
  for (int s=0;s<CS;s++){
    if (b < 8){
      int dir = b>>2, jb = (b&3)*128;
      int j = jb + (tid>>2), c0 = (tid&3)*128;
      const float* Whh = dir ? p.Whb : p.Whf;
      const float* bhh = dir ? p.bhb : p.bhf;
      const float* gi  = dir ? p.gb : p.gf;
      float* o = dir ? p.outb : p.outf;
      int pos = dir ? (CS-1-s) : s;
      const float* hp = (s>0) ? (o + (dir ? (pos+1)*CH : (s-1)*CH)) : nullptr;
      float ar=0.f, az=0.f, an=0.f;
      if (s > 0){
        const float* wr = Whh + (size_t)j*CH;
        const float* wz = Whh + (size_t)(j+CH)*CH;
        const float* wn = Whh + (size_t)(j+2*CH)*CH;
        #pragma unroll 4
        for (int k=c0;k<c0+128;k++){
          float h = hp[k];
          ar += wr[k]*h; az += wz[k]*h; an += wn[k]*h;
        }
      }
      ar += __shfl_xor(ar,1); ar += __shfl_xor(ar,2);
      az += __shfl_xor(az,1); az += __shfl_xor(az,2);
      an += __shfl_xor(an,1); an += __shfl_xor(an,2);
      if ((tid&3)==0){
        const float* g = gi + pos*CH3;
        float hpj = (s>0) ? hp[j] : 0.f;
        float r = sigm(g[j]       + ar + bhh[j]);
        float z = sigm(g[j+CH]    + az + bhh[j+CH]);
        float n = tanhf(g[j+2*CH] + r*(an + bhh[j+2*CH]));
        o[pos*CH + j] = (1.f-z)*n + z*hpj;
      }
    }
    gg.sync();
  }

  // ---------- prep2 + cov_last init ----------
  {
    int idx = b*512 + tid;
    if (idx < 2*CS*CH){
      int which = idx / (CS*CH);
      int rem = idx - which*(CS*CH);
      int s2 = rem / CH, r = rem - s2*CH;
      const float* of = p.outf + s2*CH;
      const float* ob = p.outb + s2*CH;
      const float* w2 = which ? (p.Wic + (size_t)r*CH3) : (p.ua + (size_t)r*CH2);
      float acc = 0.f;
      #pragma unroll 4
      for (int k=0;k<CH;k++) acc += w2[k]*of[k];
      #pragma unroll 4
      for (int k=0;k<CH;k++) acc += w2[CH+k]*ob[k];
      (which ? p.Aenc : p.ua_enc)[s2*CH + r] = acc;
    } else if (idx < 2*CS*CH + CH){
      p.h_carry[idx - 2*CS*CH] = p.outf[(CS-1)*CH + (idx - 2*CS*CH)];
    } else if (idx < 2*CS*CH + 2*CH){
      p.cov_last[idx - 2*CS*CH - CH] = 0.f;
    }
  }
  gg.sync();

  // ---------- initial wah + persistent cov A-fragments ----------
  i32x4 af[4][8];
  if (b == 0){
    int wv = tid>>6, l = tid&63;
    const i32x4* wp = (const i32x4*)p.w8m;
    #pragma unroll
    for (int j=0;j<4;j++){
      #pragma unroll
      for (int kb=0;kb<8;kb++)
        af[j][kb] = wp[((size_t)((4*wv+j)*8+kb))*64 + l];
      asm volatile("" ::: "memory");
    }
  } else if (b <= 2){
    int j = (b-1)*256 + (tid>>1);
    int cq = (tid&1)*256;
    const float* w2 = p.wa + (size_t)j*CH;
    float acc = 0.f;
    #pragma unroll 4
    for (int k=cq;k<cq+256;k++) acc += w2[k]*p.h_carry[k];
    acc += __shfl_xor(acc,1);
    if ((tid&1)==0) p.wah[j] = acc;
  }
  gg.sync();

  // ---------- decode loop ----------
  for (int t=0;t<CT;t++){
    // PH1: attention scores
    if (b < CS){
      int s = b, j = tid;
      float acc = p.ua_enc[s*CH + j] + p.wah[j];
      if (t > 0){
        const float* v = p.vc + (size_t)j*CH;
        const float* cvs = p.cov_vec + s*CH;
        #pragma unroll 4
        for (int k=0;k<CH;k++) acc += v[k]*cvs[k];
      }
      float val = p.va[j]*tanhf(acc);
      for (int m=1;m<64;m<<=1) val += __shfl_xor(val,m);
      if ((tid&63)==0) srd[tid>>6] = val;
      __syncthreads();
      if (tid==0){
        float sm = 0.f;
        #pragma unroll
        for (int i=0;i<8;i++) sm += srd[i];
        p.e[s] = sm;
      }
    }
    gg.sync();

    // PH2: softmax + context (block 0)
    if (b == 0){
      float v = (tid<CS) ? p.e[tid] : -1e30f;
      float m = v;
      for (int k=1;k<64;k<<=1) m = fmaxf(m, __shfl_xor(m,k));
      if ((tid&63)==0) srd[tid>>6] = m;
      __syncthreads();
      if (tid==0){
        float g = srd[0];
        #pragma unroll
        for (int i=1;i<8;i++) g = fmaxf(g, srd[i]);
        srd[0] = g;
      }
      __syncthreads();
      float gm = srd[0];
      __syncthreads();
      float ex = (tid<CS) ? expf(v-gm) : 0.f;
      float ss = ex;
      for (int k=1;k<64;k<<=1) ss += __shfl_xor(ss,k);
      if ((tid&63)==0) srd[tid>>6] = ss;
      __syncthreads();
      if (tid==0){
        float tt = 0.f;
        #pragma unroll
        for (int i=0;i<8;i++) tt += srd[i];
        srd[0] = tt;
      }
      __syncthreads();
      float inv = 1.f/srd[0];
      if (tid < CS){ float a = ex*inv; al96[tid] = a; p.alpha[tid] = a; }
      __syncthreads();
      #pragma unroll
      for (int q=0;q<2;q++){
        int d = q*512 + tid;
        const float* src = (d<CH) ? p.outf : p.outb;
        int dd = d & 511;
        float acc = 0.f;
        for (int s2=0;s2<CS;s2++) acc += al96[s2]*src[s2*CH+dd];
        p.ctx[d] = acc;
      }
    }
    gg.sync();

    // PH3: GRU (blocks 0..31) || logits ctx-half (blocks 32..)
    if (b < 32){
      int j = b*16 + (tid>>5);
      int ln = tid&31;
      const float* xd = p.x_dec + t*CE;
      float ar=0.f, az=0.f, an=0.f;
      {
        int c0 = ln*40;
        const float* wr = p.Wid + (size_t)j*CXD;
        const float* wz = p.Wid + (size_t)(j+CH)*CXD;
        const float* wn = p.Wid + (size_t)(j+2*CH)*CXD;
        for (int k=c0;k<c0+40;k++){
          float x = (k<CH2) ? p.ctx[k] : xd[k-CH2];
          ar += wr[k]*x; az += wz[k]*x; an += wn[k]*x;
        }
      }
      float hr=0.f, hz=0.f, hn2=0.f;
      {
        int c0 = ln*16;
        const float* wr = p.Whd + (size_t)j*CH;
        const float* wz = p.Whd + (size_t)(j+CH)*CH;
        const float* wn = p.Whd + (size_t)(j+2*CH)*CH;
        for (int k=c0;k<c0+16;k++){
          float hv = p.h_carry[k];
          hr += wr[k]*hv; hz += wz[k]*hv; hn2 += wn[k]*hv;
        }
      }
      for (int m=1;m<32;m<<=1){
        ar+=__shfl_xor(ar,m); az+=__shfl_xor(az,m); an+=__shfl_xor(an,m);
        hr+=__shfl_xor(hr,m); hz+=__shfl_xor(hz,m); hn2+=__shfl_xor(hn2,m);
      }
      if (ln==0){
        float hprev = p.h_carry[j];
        float r = sigm(ar + p.bid2[j]      + hr + p.bhd2[j]);
        float z = sigm(az + p.bid2[j+CH]   + hz + p.bhd2[j+CH]);
        float n = tanhf(an + p.bid2[j+2*CH] + r*(hn2 + p.bhd2[j+2*CH]));
        p.h_cur[j] = (1.f-z)*n + z*hprev;
      }
    } else {
      if (tid < 512){ ldc[tid] = p.ctx[tid]; ldc[512+tid] = p.ctx[512+tid]; }
      __syncthreads();
      int ln = tid&63;
      int nc = (NB-32)*8;
      for (int r = (b-32)*8 + (tid>>6); r < CV; r += nc){
        float acc = 0.f;
        if (BF16){
          const u32* w2 = (const u32*)((const u16*)p.Wv + (size_t)r*CH3) + 256;
          #pragma unroll
          for (int k=0;k<8;k++){
            u32 u = w2[k*64+ln];
            const float2 hp = *(const float2*)&ldc[2*(k*64+ln)];
            acc += __uint_as_float(u<<16)*hp.x + __uint_as_float(u & 0xffff0000u)*hp.y;
          }
        } else {
          const float* w2 = (const float*)p.Wv + (size_t)r*CH3 + CH;
          #pragma unroll
          for (int k=0;k<16;k++) acc += w2[k*64+ln]*ldc[k*64+ln];
        }
        for (int m=1;m<64;m<<=1) acc += __shfl_xor(acc,m);
        if (ln==0) p.lpart[r] = acc;
      }
      __syncthreads();
    }
    gg.sync();

    // PH4: cov (block 0) || wah (1,2) || logits h-half (3..)
    if (b == 0){
      const float* h_dec = (t==0) ? p.h_carry : p.h_cur;
      if (tid < 256) hd16[tid] = packh2(h_dec[2*tid], h_dec[2*tid+1]);
      __syncthreads();
      float bacc_r = 0.f;
      {
        const u32* bw = p.wic16P + tid;
        #pragma unroll 8
        for (int kp=0;kp<256;kp++)
          bacc_r = dot2f(bw[(size_t)kp*512], hd16[kp], bacc_r);
      }
      float bsum_r = p.bic[tid] + p.bhc[tid];
      float rs_r = p.rs[tid];
      float a_next = p.Aenc[tid];
      p.cov_vec[tid] = tanhf(p.cov_last[tid]);
      if (t > 0) p.h_carry[tid] = h_dec[tid];
      __syncthreads();
      int wv = tid>>6, l = tid&63;
      for (int s=0;s<CS;s++){
        if (s > 0){
          i32x4 acc0={0,0,0,0}, acc1={0,0,0,0}, acc2={0,0,0,0}, acc3={0,0,0,0};
          #pragma unroll
          for (int kb=0;kb<8;kb++){
            i32x4 bfr = *(const i32x4*)&h8w[kb*16 + (l>>4)*4];
            acc0 = __builtin_amdgcn_mfma_i32_16x16x64_i8(af[0][kb], bfr, acc0, 0,0,0);
            acc1 = __builtin_amdgcn_mfma_i32_16x16x64_i8(af[1][kb], bfr, acc1, 0,0,0);
            acc2 = __builtin_amdgcn_mfma_i32_16x16x64_i8(af[2][kb], bfr, acc2, 0,0,0);
            acc3 = __builtin_amdgcn_mfma_i32_16x16x64_i8(af[3][kb], bfr, acc3, 0,0,0);
          }
          if ((l & 15) == 0){
            int rq = l >> 4;
            *(i32x4*)&part_l[(4*wv+0)*16 + rq*4] = acc0;
            *(i32x4*)&part_l[(4*wv+1)*16 + rq*4] = acc1;
            *(i32x4*)&part_l[(4*wv+2)*16 + rq*4] = acc2;
            *(i32x4*)&part_l[(4*wv+3)*16 + rq*4] = acc3;
          }
        }
        COVBAR();
        {
          float T = (s > 0) ? (float)(int)part_l[tid] * rs_r : 0.f;
          float a_cur = a_next;
          if (s < CS-1) a_next = p.Aenc[(s+1)*CH + tid];
          float h = tanhf(T + al96[s]*(a_cur + bacc_r) + bsum_r);
          if (s < CS-1){
            int q = (int)rintf(h * 127.f);
            u32 bq = (u32)(q & 255);
            u32 p01 = bq | (__shfl_xor(bq,1) << 8);
            u32 pk = p01 | (__shfl_xor(p01,2) << 16);
            if ((tid & 3) == 0) h8w[tid >> 2] = pk;
            p.cov_vec[(s+1)*CH + tid] = tanhf(h);
          } else {
            p.cov_last[tid] = h;
          }
        }
        COVBAR();
      }
    } else if (b <= 2){
      if (t > 0){   // t=0 keeps wa@h_enc for attn(1) (reference semantics)
        int j = (b-1)*256 + (tid>>1);
        int cq = (tid&1)*256;
        const float* w2 = p.wa + (size_t)j*CH;
        float acc = 0.f;
        #pragma unroll 4
        for (int k=cq;k<cq+256;k++) acc += w2[k]*p.h_cur[k];
        acc += __shfl_xor(acc,1);
        if ((tid&1)==0) p.wah[j] = acc;
      }
    } else {
      if (tid < CH) ldh[tid] = p.h_cur[tid];
      __syncthreads();
      int ln = tid&63;
      int nh = (NB-3)*8;
      for (int r = (b-3)*8 + (tid>>6); r < CV; r += nh){
        float acc = 0.f;
        if (BF16){
          const u32* w2 = (const u32*)((const u16*)p.Wv + (size_t)r*CH3);
          #pragma unroll
          for (int k=0;k<4;k++){
            u32 u = w2[k*64+ln];
            const float2 hp = *(const float2*)&ldh[2*(k*64+ln)];
            acc += __uint_as_float(u<<16)*hp.x + __uint_as_float(u & 0xffff0000u)*hp.y;
          }
        } else {
          const float* w2 = (const float*)p.Wv + (size_t)r*CH3;
          #pragma unroll
          for (int k=0;k<8;k++) acc += w2[k*64+ln]*ldh[k*64+ln];
        }
        for (int m=1;m<64;m<<=1) acc += __shfl_xor(acc,m);
        if (ln==0) p.outp[(size_t)t*CV + r] = acc + p.lpart[r] + p.lb[r];
      }
      __syncthreads();
    }
    gg.sync();
  }
}

// ================= host =================
extern "C" void kernel_launch(void* const* d_in, const int* in_sizes, int n_in,
                              void* d_out, int out_size, void* d_ws, size_t ws_size,
                              hipStream_t stream){
  (void)in_sizes; (void)n_in; (void)out_size;
  const int*   iseq = (const int*)d_in[0];
  const int*   oseq = (const int*)d_in[1];
  const float* ee   = (const float*)d_in[2];
  const float* de   = (const float*)d_in[3];
  const float* Wih_f=(const float*)d_in[4];  const float* Whh_f=(const float*)d_in[5];
  const float* bih_f=(const float*)d_in[6];  const float* bhh_f=(const float*)d_in[7];
  const float* Wih_b=(const float*)d_in[8];  const float* Whh_b=(const float*)d_in[9];
  const float* bih_b=(const float*)d_in[10]; const float* bhh_b=(const float*)d_in[11];
  const float* Wih_d=(const float*)d_in[12]; const float* Whh_d=(const float*)d_in[13];
  const float* bih_d=(const float*)d_in[14]; const float* bhh_d=(const float*)d_in[15];
  const float* Wih_c=(const float*)d_in[16]; const float* Whh_c=(const float*)d_in[17];
  const float* bih_c=(const float*)d_in[18]; const float* bhh_c=(const float*)d_in[19];
  const float* va   =(const float*)d_in[20]; const float* wa   =(const float*)d_in[21];
  const float* ua   =(const float*)d_in[22]; const float* vc   =(const float*)d_in[23];
  const float* lin_W=(const float*)d_in[24]; const float* lin_b=(const float*)d_in[25];
  float* out = (float*)d_out;
  char* ws = (char*)d_ws;

  size_t off = 0;
  auto A = [&](size_t bytes){ size_t r = off; off = (off + bytes + 255) & ~(size_t)255; return r; };
  size_t o_w8m   = A((size_t)CH*128*4);
  size_t o_rs    = A((size_t)CH*4);
  size_t o_wicP  = A((size_t)256*512*4);
  size_t o_xenc = A((size_t)CS*CE*4), o_xdec = A((size_t)CT*CE*4);
  size_t o_gf   = A((size_t)CS*CH3*4), o_gb  = A((size_t)CS*CH3*4);
  size_t o_of   = A((size_t)CS*CH*4),  o_ob  = A((size_t)CS*CH*4);
  size_t o_uae  = A((size_t)CS*CH*4),  o_Ae  = A((size_t)CS*CH*4);
  size_t o_e    = A(CS*4), o_al = A(CS*4), o_ctx = A(CH2*4);
  size_t o_hc   = A(CH*4), o_hn = A(CH*4), o_cl = A(CH*4);
  size_t o_wah  = A(CH*4);
  size_t o_cv   = A((size_t)CS*CH*4);
  size_t o_lp   = A((size_t)CV*4);
  size_t o_lwb  = A((size_t)CV*CH3*2);
  bool use16 = (off <= ws_size);

  uint4* w8m = (uint4*)(ws+o_w8m);    float* rs = (float*)(ws+o_rs);
  u32* wic16P = (u32*)(ws+o_wicP);
  float* x_enc = (float*)(ws+o_xenc); float* x_dec = (float*)(ws+o_xdec);
  float* gf = (float*)(ws+o_gf);      float* gb = (float*)(ws+o_gb);
  float* outf = (float*)(ws+o_of);    float* outb = (float*)(ws+o_ob);
  float* ua_enc = (float*)(ws+o_uae); float* Aenc = (float*)(ws+o_Ae);
  float* e = (float*)(ws+o_e);        float* alpha = (float*)(ws+o_al);
  float* ctx = (float*)(ws+o_ctx);
  float* h_carry = (float*)(ws+o_hc); float* h_cur = (float*)(ws+o_hn);
  float* cov_last = (float*)(ws+o_cl);
  float* wah = (float*)(ws+o_wah);
  float* cov_vec = (float*)(ws+o_cv);
  float* lpart = (float*)(ws+o_lp);
  u16* lwb = (u16*)(ws+o_lwb);

  // ---- pre-launches (independent of encoder) ----
  k_embed<<<CS,256,0,stream>>>(iseq, oseq, ee, de, x_enc, x_dec);
  k_gi<<<(2*CS*CH3)/256,256,0,stream>>>(Wih_f,bih_f,Wih_b,bih_b,x_enc,gf,gb);
  k_cvt_cov<<<(256*512)/256,256,0,stream>>>(Wih_c, wic16P);
  k_quant<<<CH,64,0,stream>>>(Whh_c, w8m, rs);
  if (use16)
    k_cvt<<<2048,256,0,stream>>>(lin_W, lwb, CV*CH3);

  const void* Wv = use16 ? (const void*)lwb : (const void*)lin_W;

  MP mp;
  mp.Whf=Whh_f; mp.bhf=bhh_f; mp.Whb=Whh_b; mp.bhb=bhh_b; mp.gf=gf; mp.gb=gb;
  mp.outf=outf; mp.outb=outb;
  mp.ua=ua; mp.Wic=Wih_c;
  mp.ua_enc=ua_enc; mp.Aenc=Aenc; mp.h_carry=h_carry;
  mp.wa=wa; mp.wah=wah;
  mp.vc=vc; mp.va=va;
  mp.e=e; mp.alpha=alpha; mp.ctx=ctx;
  mp.Wid=Wih_d; mp.bid2=bih_d; mp.Whd=Whh_d; mp.bhd2=bhh_d; mp.x_dec=x_dec;
  mp.h_cur=h_cur;
  mp.Wv=Wv; mp.lb=lin_b;
  mp.outp=out; mp.lpart=lpart;
  mp.w8m=w8m; mp.rs=rs; mp.wic16P=wic16P;
  mp.bic=bih_c; mp.bhc=bhh_c;
  mp.cov_vec=cov_vec; mp.cov_last=cov_last;

  void* kargs[] = { &mp };
  hipError_t cerr;
  if (use16)
    cerr = hipLaunchCooperativeKernel((const void*)&k_mega<1>, dim3(256), dim3(512), kargs, 0, stream);
  else
    cerr = hipLaunchCooperativeKernel((const void*)&k_mega<0>, dim3(256), dim3(512), kargs, 0, stream);

  if (cerr != hipSuccess){
    // ---- fallback: proven r14 multi-launch path ----
    k_init<<<1,256,0,stream>>>(cov_last);
    for (int s=0;s<CS;s++)
      k_enc_step<<<16,256,0,stream>>>(s, Whh_f,bhh_f,Whh_b,bhh_b, gf,gb, outf,outb);
    k_prep2<<<(2*CS*CH+CH)/256,256,0,stream>>>(ua, Wih_c, outf, outb, ua_enc, Aenc, h_carry);
    k_wah<<<8,256,0,stream>>>(wa, h_carry, wah);
    for (int t=0;t<CT;t++){
      k_attn<<<CS,256,0,stream>>>(t, vc, va, ua_enc, cov_vec, wah, e);
      k_soft<<<1,128,0,stream>>>(e, outf, outb, alpha, ctx);
      k_gru<<<64,256,0,stream>>>(t, Wih_d,bih_d,Whh_d,bhh_d, ctx, x_dec, h_carry, h_cur);
      if (use16)
        k_tail<1><<<103,512,0,stream>>>(t, (const void*)lwb, lin_b, h_cur, ctx, out, wa, wah,
                                        w8m, rs, wic16P, bih_c, bhh_c, Aenc, alpha,
                                        cov_vec, cov_last, h_carry);
      else
        k_tail<0><<<103,512,0,stream>>>(t, (const void*)lin_W, lin_b, h_cur, ctx, out, wa, wah,
                                        w8m, rs, wic16P, bih_c, bhh_c, Aenc, alpha,
                                        cov_vec, cov_last, h_carry);
    }
  }
}

// Round 16
// 23880.481 us; speedup vs baseline: 2.1202x; 2.1202x over previous
//
#include <hip/hip_runtime.h>
#include <hip/hip_bf16.h>
#include <hip/hip_fp16.h>
#include <math.h>

#define CS 96      // source len
#define CT 96      // target len
#define CE 256     // embed
#define CH 512     // hidden
#define CH2 1024
#define CH3 1536
#define CV 32000
#define CXD 1280   // E + 2H

typedef unsigned int u32;
typedef unsigned short u16;
typedef unsigned long long u64;
typedef __attribute__((ext_vector_type(4))) int i32x4;

__device__ __forceinline__ float sigm(float x){ return 1.f/(1.f+expf(-x)); }

__device__ __forceinline__ float dot2f(u32 a, u32 b, float c){
#if __has_builtin(__builtin_amdgcn_fdot2)
  typedef _Float16 hv2 __attribute__((ext_vector_type(2)));
  hv2 x = __builtin_bit_cast(hv2, a), y = __builtin_bit_cast(hv2, b);
  return __builtin_amdgcn_fdot2(x, y, c, false);
#else
  __half2 x = __builtin_bit_cast(__half2, a), y = __builtin_bit_cast(__half2, b);
  return c + __half2float(x.x)*__half2float(y.x) + __half2float(x.y)*__half2float(y.y);
#endif
}

__device__ __forceinline__ u32 packh2(float a, float b){
  return (u32)__half_as_ushort(__float2half(a)) | ((u32)__half_as_ushort(__float2half(b)) << 16);
}

// proven fence-free tagged read: spin until tag >= want, return payload f32
__device__ __forceinline__ float spinf(const u64* p, u32 want){
  u64 x; int g = 0;
  do { x = __hip_atomic_load(p, __ATOMIC_RELAXED, __HIP_MEMORY_SCOPE_AGENT); }
  while ((u32)(x>>32) < want && ++g < 200000);   // bounded: never hangs
  return __uint_as_float((u32)x);
}
__device__ __forceinline__ void tagstore(u64* p, u32 tag, float v){
  __hip_atomic_store(p, ((u64)tag<<32) | (u64)__float_as_uint(v),
                     __ATOMIC_RELAXED, __HIP_MEMORY_SCOPE_AGENT);
}

#define COVBAR() do{ asm volatile("s_waitcnt lgkmcnt(0)" ::: "memory"); \
                     __builtin_amdgcn_sched_barrier(0); \
                     __builtin_amdgcn_s_barrier(); \
                     __builtin_amdgcn_sched_barrier(0); }while(0)

// ---------------- init: zero ALL tag buffers (replay-safe) + cov_last ----------------
__global__ void k_init(u64* tags, int ntags, float* cov_last){
  int i = blockIdx.x*blockDim.x + threadIdx.x;
  int stride = gridDim.x*blockDim.x;
  for (int j=i; j<ntags; j+=stride) tags[j] = 0ull;
  for (int j=i; j<CH; j+=stride) cov_last[j] = 0.f;
}

// ---------------- embedding gathers ----------------
__global__ void k_embed(const int* iseq, const int* oseq, const float* ee, const float* de,
                        float* x_enc, float* x_dec){
  int s = blockIdx.x, d = threadIdx.x;
  x_enc[s*CE+d] = ee[(long)iseq[s]*CE + d];
  x_dec[s*CE+d] = de[(long)oseq[s]*CE + d];
}

// ---------------- encoder input-gate precompute ----------------
__global__ void k_gi(const float* Wf, const float* bf, const float* Wb, const float* bb,
                     const float* x_enc, float* gf, float* gb){
  int idx = blockIdx.x*256 + threadIdx.x;
  int dir = idx / (CS*CH3);
  int rem = idx - dir*(CS*CH3);
  int s = rem / CH3, r = rem - s*CH3;
  const float* W = dir ? Wb : Wf;
  const float* b = dir ? bb : bf;
  const float* x = x_enc + s*CE;
  const float* w = W + (long)r*CE;
  float acc = b[r];
  #pragma unroll 8
  for (int k=0;k<CE;k++) acc += w[k]*x[k];
  (dir ? gb : gf)[s*CH3 + r] = acc;
}

// ---------------- fused bidirectional encoder: ONE launch, 16 co-resident blocks ----------------
__launch_bounds__(512)
__global__ void k_enc_f(const float* Whf, const float* bhf, const float* Whb, const float* bhb,
                        const float* gf, const float* gb, float* outf, float* outb, u64* hx){
  int b = blockIdx.x, tid = threadIdx.x;
  int dir = b >> 3;
  const float* Whh = dir ? Whb : Whf;
  const float* bhh = dir ? bhb : bhf;
  const float* gi  = dir ? gb : gf;
  float* o = dir ? outb : outf;
  u64* hxd = hx + (size_t)dir*CH;
  int jl = (b&7)*64 + (tid>>3);    // own row
  int part = tid&7, c0 = part*64;
  __shared__ float hl[CH];

  for (int s=0;s<CS;s++){
    if (s > 0){
      if (tid < 64){
        #pragma unroll
        for (int i=0;i<8;i++){ int idx = i*64+tid; hl[idx] = spinf(&hxd[idx], (u32)s); }
      }
      __syncthreads();
    }
    int pos = dir ? (CS-1-s) : s;
    float ar=0.f, az=0.f, an=0.f;
    if (s > 0){
      const float* wr = Whh + (size_t)jl*CH;
      const float* wz = Whh + (size_t)(jl+CH)*CH;
      const float* wn = Whh + (size_t)(jl+2*CH)*CH;
      #pragma unroll 4
      for (int k=c0;k<c0+64;k++){
        float h = hl[k];
        ar += wr[k]*h; az += wz[k]*h; an += wn[k]*h;
      }
    }
    ar += __shfl_xor(ar,1); ar += __shfl_xor(ar,2); ar += __shfl_xor(ar,4);
    az += __shfl_xor(az,1); az += __shfl_xor(az,2); az += __shfl_xor(az,4);
    an += __shfl_xor(an,1); an += __shfl_xor(an,2); an += __shfl_xor(an,4);
    if (part == 0){
      const float* g = gi + pos*CH3;
      float hpj = (s>0) ? hl[jl] : 0.f;
      float r = sigm(g[jl]       + ar + bhh[jl]);
      float z = sigm(g[jl+CH]    + az + bhh[jl+CH]);
      float n = tanhf(g[jl+2*CH] + r*(an + bhh[jl+2*CH]));
      float h = (1.f-z)*n + z*hpj;
      o[pos*CH + jl] = h;
      tagstore(&hxd[jl], (u32)(s+1), h);
    }
    __syncthreads();   // all hl reads done before next spin overwrites
  }
}

// ---------------- ua_enc / Aenc precompute + hE init ----------------
__global__ void k_prep2(const float* ua, const float* Wic, const float* outf, const float* outb,
                        float* ua_enc, float* Aenc, float* h_carry){
  int idx = blockIdx.x*256 + threadIdx.x;
  if (idx < 2*CS*CH){
    int which = idx / (CS*CH);
    int rem = idx - which*(CS*CH);
    int s = rem / CH, r = rem - s*CH;
    const float* of = outf + s*CH;
    const float* ob = outb + s*CH;
    const float* w = which ? (Wic + (long)r*CH3) : (ua + (long)r*CH2);
    float acc = 0.f;
    #pragma unroll 4
    for (int k=0;k<CH;k++) acc += w[k]*of[k];
    #pragma unroll 4
    for (int k=0;k<CH;k++) acc += w[CH+k]*ob[k];
    (which ? Aenc : ua_enc)[s*CH + r] = acc;
  } else if (idx < 2*CS*CH + CH){
    int j = idx - 2*CS*CH;
    h_carry[j] = outf[(CS-1)*CH + j];
  }
}

// ---------------- fp32 -> bf16 (RNE) for lin_W ----------------
__global__ void k_cvt(const float* w, u16* o, int n){
  int i = blockIdx.x*blockDim.x + threadIdx.x;
  int stride = gridDim.x*blockDim.x;
  for (; i<n; i+=stride){
    union { float f; u32 u; } v; v.f = w[i];
    u32 r = (v.u + 0x7fffu + ((v.u>>16)&1u)) >> 16;
    o[i] = (u16)r;
  }
}

// ---------------- Wih_c[:,1024:1536] -> packed-transposed fp16 ----------------
__global__ void k_cvt_cov(const float* Wic, u32* wic16P){
  int i = blockIdx.x*256 + threadIdx.x;
  int kp = i >> 9, r = i & 511;
  float a = Wic[(size_t)r*CH3 + CH2 + 2*kp];
  float b = Wic[(size_t)r*CH3 + CH2 + 2*kp + 1];
  wic16P[(size_t)kp*512 + r] = packh2(a, b);
}

// ---------------- Whh_c -> i8 MFMA A-fragment layout ----------------
__global__ void k_quant(const float* Whc, uint4* w8m, float* rs){
  int r = blockIdx.x;
  int l = threadIdx.x;
  const float* wr = Whc + (size_t)r*CH;
  float m = 0.f;
  for (int k=l; k<CH; k+=64) m = fmaxf(m, fabsf(wr[k]));
  for (int d=1; d<64; d<<=1) m = fmaxf(m, __shfl_xor(m,d));
  float sc = (m > 0.f) ? (127.f/m) : 0.f;
  if (l < 32){
    int kb = l>>2, q = l&3;
    u32 wv[4];
    #pragma unroll
    for (int wi=0;wi<4;wi++){
      u32 p = 0;
      #pragma unroll
      for (int j=0;j<4;j++){
        int v = (int)rintf(wr[kb*64 + q*16 + wi*4 + j]*sc);
        v = max(-127, min(127, v));
        p |= (u32)(v & 255) << (8*j);
      }
      wv[wi] = p;
    }
    int tile = (r>>4)*8 + kb;
    int lane = q*16 + (r&15);
    w8m[(size_t)tile*64 + lane] = make_uint4(wv[0],wv[1],wv[2],wv[3]);
  }
  if (l==0) rs[r] = m/(127.f*127.f);
}

// ---------------- wah = wa @ h (pre-loop only, for e(0)) ----------------
__global__ void k_wah(const float* wa, const float* h, float* wah){
  int j = blockIdx.x*64 + (threadIdx.x>>2);
  int c0 = (threadIdx.x&3)*128;
  const float* w = wa + (long)j*CH;
  float acc = 0.f;
  #pragma unroll 4
  for (int k=c0;k<c0+128;k++) acc += w[k]*h[k];
  acc += __shfl_xor(acc,1); acc += __shfl_xor(acc,2);
  if ((threadIdx.x&3)==0) wah[j] = acc;
}

// ---------------- attn scores for t=0 only (no cov term) ----------------
__global__ void k_attn0(const float* va, const float* ua_enc, const float* wah, float* e){
  int s = blockIdx.x, tid = threadIdx.x;
  __shared__ float red[4];
  float sum = 0.f;
  #pragma unroll
  for (int jj=0;jj<2;jj++){
    int j = tid + jj*256;
    float acc = ua_enc[s*CH + j] + wah[j];
    sum += va[j]*tanhf(acc);
  }
  for (int m=1;m<64;m<<=1) sum += __shfl_xor(sum,m);
  if ((tid&63)==0) red[tid>>6] = sum;
  __syncthreads();
  if (tid==0) e[s] = red[0]+red[1]+red[2]+red[3];
}

// ================= fused decode step: ONE launch, 129 co-resident blocks =================
// b=0: cov (i8 MFMA, r14 body).  b=1..96: h-spin -> logits-A -> cov-row spin -> attn -> e(t+1).
// b=97..128: gru -> publish h_cur tagged -> h-spin -> logits-B.
template<int BF16>
__launch_bounds__(512, 2)
__global__ void k_step(int t, const void* Wv, const float* lb, const float* hE,
                       u64* hc64, const float* x_dec,
                       const float* eR, float* eW,
                       const float* outf, const float* outb,
                       const float* wa, const float* vc, const float* va, const float* ua_enc,
                       const float* Wid, const float* bid, const float* Whd, const float* bhd,
                       const uint4* w8m, const float* rs, const u32* wic16P,
                       const float* bic, const float* bhc, const float* Aenc,
                       u64* cv64, float* cov_last, float* out){
  int b = blockIdx.x, tid = threadIdx.x;
  u32 wantH = (u32)(t+1);
  u64* hcW = hc64 + (size_t)(t&1)*CH;         // this step's h_cur (tagged)
  const u64* hcR = hc64 + (size_t)((t+1)&1)*CH; // previous step's h_cur (plain, via boundary)

  __shared__ float el[CS], al[CS];
  __shared__ float ctxl[CH2];
  __shared__ float hl[CH];
  __shared__ float he2[CH];
  __shared__ float red[8];
  __shared__ u32 part_l[CH];
  __shared__ __align__(16) u32 h8w[128];
  __shared__ u32 hd16[256];
  __shared__ float cvsl[CH];

  // ---- common: softmax(e(t)) redundantly per block ----
  if (tid < CS) el[tid] = eR[tid];
  __syncthreads();
  if (tid == 0){
    float m = -1e30f;
    for (int s=0;s<CS;s++) m = fmaxf(m, el[s]);
    float sm = 0.f;
    for (int s=0;s<CS;s++){ float ex = expf(el[s]-m); al[s] = ex; sm += ex; }
    float inv = 1.f/sm;
    for (int s=0;s<CS;s++) al[s] *= inv;
  }
  __syncthreads();
  if (b != 0){
    // ctx = alpha @ [outf|outb]
    float a0=0.f, a1=0.f;
    for (int s=0;s<CS;s++){ a0 += al[s]*outf[s*CH+tid]; a1 += al[s]*outb[s*CH+tid]; }
    ctxl[tid] = a0; ctxl[CH+tid] = a1;
  }

  if (b == 0){
    // ================= coverage =================
    if (t == 0){ if (tid < CH) hl[tid] = hE[tid]; }
    else if (tid < 64){
      #pragma unroll
      for (int i=0;i<8;i++){ int idx=i*64+tid; hl[idx] = spinf(&hcW[idx], wantH); }
    }
    __syncthreads();
    if (tid < 256) hd16[tid] = packh2(hl[2*tid], hl[2*tid+1]);
    __syncthreads();
    float bacc_r = 0.f;
    {
      const u32* bw = wic16P + tid;
      #pragma unroll 8
      for (int kp=0;kp<256;kp++)
        bacc_r = dot2f(bw[(size_t)kp*512], hd16[kp], bacc_r);
    }
    i32x4 af[4][8];
    {
      int w = tid>>6, l = tid&63;
      const i32x4* wp = (const i32x4*)w8m;
      #pragma unroll
      for (int j=0;j<4;j++){
        #pragma unroll
        for (int kb=0;kb<8;kb++)
          af[j][kb] = wp[((size_t)((4*w+j)*8+kb))*64 + l];
        asm volatile("" ::: "memory");
      }
    }
    float bsum_r = bic[tid] + bhc[tid];
    float rs_r = rs[tid];
    float a_next = Aenc[tid];
    tagstore(&cv64[tid], wantH, tanhf(cov_last[tid]));    // row 0
    __syncthreads();

    int w = tid>>6, l = tid&63;
    for (int s=0;s<CS;s++){
      if (s > 0){
        i32x4 acc0={0,0,0,0}, acc1={0,0,0,0}, acc2={0,0,0,0}, acc3={0,0,0,0};
        #pragma unroll
        for (int kb=0;kb<8;kb++){
          i32x4 bfr = *(const i32x4*)&h8w[kb*16 + (l>>4)*4];
          acc0 = __builtin_amdgcn_mfma_i32_16x16x64_i8(af[0][kb], bfr, acc0, 0,0,0);
          acc1 = __builtin_amdgcn_mfma_i32_16x16x64_i8(af[1][kb], bfr, acc1, 0,0,0);
          acc2 = __builtin_amdgcn_mfma_i32_16x16x64_i8(af[2][kb], bfr, acc2, 0,0,0);
          acc3 = __builtin_amdgcn_mfma_i32_16x16x64_i8(af[3][kb], bfr, acc3, 0,0,0);
        }
        if ((l & 15) == 0){
          int rq = l >> 4;
          *(i32x4*)&part_l[(4*w+0)*16 + rq*4] = acc0;
          *(i32x4*)&part_l[(4*w+1)*16 + rq*4] = acc1;
          *(i32x4*)&part_l[(4*w+2)*16 + rq*4] = acc2;
          *(i32x4*)&part_l[(4*w+3)*16 + rq*4] = acc3;
        }
      }
      COVBAR();
      {
        float T = (s > 0) ? (float)(int)part_l[tid] * rs_r : 0.f;
        float a_cur = a_next;
        if (s < CS-1) a_next = Aenc[(s+1)*CH + tid];
        float h = tanhf(T + al[s]*(a_cur + bacc_r) + bsum_r);
        if (s < CS-1){
          int q = (int)rintf(h * 127.f);
          u32 bq = (u32)(q & 255);
          u32 p01 = bq | (__shfl_xor(bq,1) << 8);
          u32 p = p01 | (__shfl_xor(p01,2) << 16);
          if ((tid & 3) == 0) h8w[tid >> 2] = p;
          tagstore(&cv64[(size_t)(s+1)*CH + tid], wantH, tanhf(h));
        } else {
          cov_last[tid] = h;
        }
      }
      COVBAR();
    }
    return;
  }

  if (b >= 97){
    // ================= gru + logits-B =================
    if (t <= 1){ if (tid < CH) he2[tid] = hE[tid]; }
    else       { if (tid < CH) he2[tid] = __uint_as_float((u32)hcR[tid]); }
    __syncthreads();
    {
      int j = (b-97)*16 + (tid>>5);
      int ln = tid&31;
      const float* xd = x_dec + t*CE;
      float ar=0.f, az=0.f, an=0.f;
      {
        int c0 = ln*40;
        const float* wr = Wid + (size_t)j*CXD;
        const float* wz = Wid + (size_t)(j+CH)*CXD;
        const float* wn = Wid + (size_t)(j+2*CH)*CXD;
        for (int k=c0;k<c0+40;k++){
          float x = (k<CH2) ? ctxl[k] : xd[k-CH2];
          ar += wr[k]*x; az += wz[k]*x; an += wn[k]*x;
        }
      }
      float hr=0.f, hz=0.f, hn2=0.f;
      {
        int c0 = ln*16;
        const float* wr = Whd + (size_t)j*CH;
        const float* wz = Whd + (size_t)(j+CH)*CH;
        const float* wn = Whd + (size_t)(j+2*CH)*CH;
        for (int k=c0;k<c0+16;k++){
          float hv = he2[k];
          hr += wr[k]*hv; hz += wz[k]*hv; hn2 += wn[k]*hv;
        }
      }
      for (int m=1;m<32;m<<=1){
        ar+=__shfl_xor(ar,m); az+=__shfl_xor(az,m); an+=__shfl_xor(an,m);
        hr+=__shfl_xor(hr,m); hz+=__shfl_xor(hz,m); hn2+=__shfl_xor(hn2,m);
      }
      if (ln==0){
        float hprev = he2[j];
        float r = sigm(ar + bid[j]       + hr + bhd[j]);
        float z = sigm(az + bid[j+CH]    + hz + bhd[j+CH]);
        float n = tanhf(an + bid[j+2*CH] + r*(hn2 + bhd[j+2*CH]));
        tagstore(&hcW[j], wantH, (1.f-z)*n + z*hprev);
      }
    }
    // full h_cur for logits
    if (tid < 64){
      #pragma unroll
      for (int i=0;i<8;i++){ int idx=i*64+tid; hl[idx] = spinf(&hcW[idx], wantH); }
    }
    __syncthreads();
    {
      int ln = tid&63;
      int gw = (b-97)*8 + (tid>>6);    // 0..255
      float x[24];
      #pragma unroll
      for (int k=0;k<24;k++){
        int c = k*64 + ln;
        x[k] = (c<CH) ? hl[c] : ctxl[c];   // note: ctxl index = c-CH+CH? see below
      }
      // fix: x layout is [h(512); ctx(1024)]
      #pragma unroll
      for (int k=0;k<24;k++){
        int c = k*64 + ln;
        x[k] = (c<CH) ? hl[c] : ctxl[c-CH];
      }
      for (int r=24000+gw; r<CV; r+=256){
        float acc = 0.f;
        if (BF16){
          const u16* w = (const u16*)Wv + (size_t)r*CH3;
          #pragma unroll
          for (int k=0;k<24;k++){
            u32 u = (u32)w[k*64+ln] << 16;
            acc += __uint_as_float(u)*x[k];
          }
        } else {
          const float* w = (const float*)Wv + (size_t)r*CH3;
          #pragma unroll
          for (int k=0;k<24;k++) acc += w[k*64+ln]*x[k];
        }
        for (int m=1;m<64;m<<=1) acc += __shfl_xor(acc,m);
        if (ln==0) out[(size_t)t*CV + r] = acc + lb[r];
      }
    }
    return;
  }

  // ================= attn blocks: logits-A + attention =================
  int s = b - 1;
  if (t == 0){ if (tid < CH) he2[tid] = hE[tid]; }
  if (tid < 64){
    #pragma unroll
    for (int i=0;i<8;i++){ int idx=i*64+tid; hl[idx] = spinf(&hcW[idx], wantH); }
  }
  __syncthreads();
  {
    int ln = tid&63;
    int gw = (b-1)*8 + (tid>>6);    // 0..767
    float x[24];
    #pragma unroll
    for (int k=0;k<24;k++){
      int c = k*64 + ln;
      x[k] = (c<CH) ? hl[c] : ctxl[c-CH];
    }
    for (int r=gw; r<24000; r+=768){
      float acc = 0.f;
      if (BF16){
        const u16* w = (const u16*)Wv + (size_t)r*CH3;
        #pragma unroll
        for (int k=0;k<24;k++){
          u32 u = (u32)w[k*64+ln] << 16;
          acc += __uint_as_float(u)*x[k];
        }
      } else {
        const float* w = (const float*)Wv + (size_t)r*CH3;
        #pragma unroll
        for (int k=0;k<24;k++) acc += w[k*64+ln]*x[k];
      }
      for (int m=1;m<64;m<<=1) acc += __shfl_xor(acc,m);
      if (ln==0) out[(size_t)t*CV + r] = acc + lb[r];
    }
  }
  // cov row s (produced this launch, tag t+1)
  if (tid < 64){
    #pragma unroll
    for (int i=0;i<8;i++){ int idx=i*64+tid; cvsl[idx] = spinf(&cv64[(size_t)s*CH+idx], wantH); }
  }
  __syncthreads();
  {
    int j = tid;
    const float* hw = (t==0) ? he2 : hl;
    const float* wr = wa + (size_t)j*CH;
    float wacc = 0.f;
    #pragma unroll 4
    for (int k=0;k<CH;k++) wacc += wr[k]*hw[k];
    float acc = ua_enc[s*CH + j] + wacc;
    const float* v = vc + (size_t)j*CH;
    #pragma unroll 4
    for (int k=0;k<CH;k++) acc += v[k]*cvsl[k];
    float val = va[j]*tanhf(acc);
    for (int m=1;m<64;m<<=1) val += __shfl_xor(val,m);
    if ((tid&63)==0) red[tid>>6] = val;
    __syncthreads();
    if (tid==0){
      float sm = 0.f;
      #pragma unroll
      for (int i=0;i<8;i++) sm += red[i];
      eW[s] = sm;
    }
  }
}

// ================= host =================
extern "C" void kernel_launch(void* const* d_in, const int* in_sizes, int n_in,
                              void* d_out, int out_size, void* d_ws, size_t ws_size,
                              hipStream_t stream){
  (void)in_sizes; (void)n_in; (void)out_size;
  const int*   iseq = (const int*)d_in[0];
  const int*   oseq = (const int*)d_in[1];
  const float* ee   = (const float*)d_in[2];
  const float* de   = (const float*)d_in[3];
  const float* Wih_f=(const float*)d_in[4];  const float* Whh_f=(const float*)d_in[5];
  const float* bih_f=(const float*)d_in[6];  const float* bhh_f=(const float*)d_in[7];
  const float* Wih_b=(const float*)d_in[8];  const float* Whh_b=(const float*)d_in[9];
  const float* bih_b=(const float*)d_in[10]; const float* bhh_b=(const float*)d_in[11];
  const float* Wih_d=(const float*)d_in[12]; const float* Whh_d=(const float*)d_in[13];
  const float* bih_d=(const float*)d_in[14]; const float* bhh_d=(const float*)d_in[15];
  const float* Wih_c=(const float*)d_in[16]; const float* Whh_c=(const float*)d_in[17];
  const float* bih_c=(const float*)d_in[18]; const float* bhh_c=(const float*)d_in[19];
  const float* va   =(const float*)d_in[20]; const float* wa   =(const float*)d_in[21];
  const float* ua   =(const float*)d_in[22]; const float* vc   =(const float*)d_in[23];
  const float* lin_W=(const float*)d_in[24]; const float* lin_b=(const float*)d_in[25];
  float* out = (float*)d_out;
  char* ws = (char*)d_ws;

  size_t off = 0;
  auto A = [&](size_t bytes){ size_t r = off; off = (off + bytes + 255) & ~(size_t)255; return r; };
  size_t o_w8m   = A((size_t)CH*128*4);
  size_t o_rs    = A((size_t)CH*4);
  size_t o_wicP  = A((size_t)256*512*4);
  size_t o_tags  = A((size_t)(1024 + 1024 + CS*CH)*8);   // hx | hc64 | cv64
  size_t o_xenc = A((size_t)CS*CE*4), o_xdec = A((size_t)CT*CE*4);
  size_t o_gf   = A((size_t)CS*CH3*4), o_gb  = A((size_t)CS*CH3*4);
  size_t o_of   = A((size_t)CS*CH*4),  o_ob  = A((size_t)CS*CH*4);
  size_t o_uae  = A((size_t)CS*CH*4),  o_Ae  = A((size_t)CS*CH*4);
  size_t o_e0   = A(CS*4), o_e1 = A(CS*4);
  size_t o_hE   = A(CH*4), o_cl = A(CH*4);
  size_t o_wah  = A(CH*4);
  size_t o_lwb  = A((size_t)CV*CH3*2);
  bool use16 = (off <= ws_size);

  uint4* w8m = (uint4*)(ws+o_w8m);    float* rs = (float*)(ws+o_rs);
  u32* wic16P = (u32*)(ws+o_wicP);
  u64* tags = (u64*)(ws+o_tags);
  u64* hx   = tags;
  u64* hc64 = tags + 1024;
  u64* cv64 = tags + 2048;
  int ntags = 1024 + 1024 + CS*CH;
  float* x_enc = (float*)(ws+o_xenc); float* x_dec = (float*)(ws+o_xdec);
  float* gf = (float*)(ws+o_gf);      float* gb = (float*)(ws+o_gb);
  float* outf = (float*)(ws+o_of);    float* outb = (float*)(ws+o_ob);
  float* ua_enc = (float*)(ws+o_uae); float* Aenc = (float*)(ws+o_Ae);
  float* eb0 = (float*)(ws+o_e0);     float* eb1 = (float*)(ws+o_e1);
  float* hE = (float*)(ws+o_hE);      float* cov_last = (float*)(ws+o_cl);
  float* wah = (float*)(ws+o_wah);
  u16* lwb = (u16*)(ws+o_lwb);

  k_init<<<64,256,0,stream>>>(tags, ntags, cov_last);
  k_embed<<<CS,256,0,stream>>>(iseq, oseq, ee, de, x_enc, x_dec);
  k_gi<<<(2*CS*CH3)/256,256,0,stream>>>(Wih_f,bih_f,Wih_b,bih_b,x_enc,gf,gb);
  k_cvt_cov<<<(256*512)/256,256,0,stream>>>(Wih_c, wic16P);
  k_quant<<<CH,64,0,stream>>>(Whh_c, w8m, rs);
  if (use16)
    k_cvt<<<2048,256,0,stream>>>(lin_W, lwb, CV*CH3);
  k_enc_f<<<16,512,0,stream>>>(Whh_f,bhh_f,Whh_b,bhh_b, gf,gb, outf,outb, hx);
  k_prep2<<<(2*CS*CH+CH)/256,256,0,stream>>>(ua, Wih_c, outf, outb, ua_enc, Aenc, hE);
  k_wah<<<8,256,0,stream>>>(wa, hE, wah);
  k_attn0<<<CS,256,0,stream>>>(va, ua_enc, wah, eb0);

  const void* Wv = use16 ? (const void*)lwb : (const void*)lin_W;
  for (int t=0;t<CT;t++){
    const float* eR = (t&1) ? eb1 : eb0;
    float*       eW = (t&1) ? eb0 : eb1;
    if (use16)
      k_step<1><<<129,512,0,stream>>>(t, Wv, lin_b, hE, hc64, x_dec, eR, eW,
                                      outf, outb, wa, vc, va, ua_enc,
                                      Wih_d, bih_d, Whh_d, bhh_d,
                                      w8m, rs, wic16P, bih_c, bhh_c, Aenc,
                                      cv64, cov_last, out);
    else
      k_step<0><<<129,512,0,stream>>>(t, Wv, lin_b, hE, hc64, x_dec, eR, eW,
                                      outf, outb, wa, vc, va, ua_enc,
                                      Wih_d, bih_d, Whh_d, bhh_d,
                                      w8m, rs, wic16P, bih_c, bhh_c, Aenc,
                                      cv64, cov_last, out);
  }
}